// Round 2
// baseline (1537.726 us; speedup 1.0000x reference)
//
#include <hip/hip_runtime.h>

#define E  4096
#define NN 16384
#define HH 256
#define WL_CAP 2048
#define REF_SLOTS 256
#define QT 16
#define MARGIN 0.0625f

typedef __attribute__((ext_vector_type(4))) float f32x4;
typedef __attribute__((ext_vector_type(8))) short bf16x8;

// round-to-nearest-even fp32 -> bf16 (inputs are finite Gaussians; no NaN path)
static __device__ __forceinline__ unsigned short f2bf(float f) {
    unsigned int u = __float_as_uint(f);
    u += 0x7fffu + ((u >> 16) & 1u);
    return (unsigned short)(u >> 16);
}
static __device__ __forceinline__ float bf2f(unsigned short h) {
    return __uint_as_float((unsigned int)h << 16);
}

// ---------------------------------------------------------------------------
// init: zero the refine-worklist counter (ws is poisoned 0xAA every call)
// ---------------------------------------------------------------------------
__global__ void init_kernel(int* cnt) { if (threadIdx.x == 0) *cnt = 0; }

// ---------------------------------------------------------------------------
// Kernel 1: K64[h,e] = sum_k X[hub[h],k] * Wk[e,k] + bk[e]   (fp64 accum)
// Also writes K64T[e,h] for coalesced refine reads. Deterministic per-row
// summation order => duplicate hub rows are BITWISE identical (np.argmax
// first-max tie-break then matches by position). No atomics for this reason.
// ---------------------------------------------------------------------------
__global__ __launch_bounds__(256) void k_proj64_kernel(
    const float* __restrict__ X, const int* __restrict__ hub,
    const float* __restrict__ Wk, const float* __restrict__ bk,
    double* __restrict__ K64, double* __restrict__ K64T)
{
    __shared__ double As[16][68];
    __shared__ double Bs[16][68];
    __shared__ int rows[64];

    const int t  = threadIdx.x;
    const int m0 = blockIdx.y * 64;   // hub rows
    const int n0 = blockIdx.x * 64;   // e cols

    if (t < 64) rows[t] = hub[m0 + t];
    __syncthreads();

    const int tx = t & 15, ty = t >> 4;
    const int kI = (t & 3) * 4, rr = t >> 2;   // rr 0..63

    double acc[4][4] = {};

    for (int k0 = 0; k0 < E; k0 += 16) {
        const float4 a4 = *(const float4*)&X[(size_t)rows[rr] * E + k0 + kI];
        As[kI + 0][rr] = (double)a4.x; As[kI + 1][rr] = (double)a4.y;
        As[kI + 2][rr] = (double)a4.z; As[kI + 3][rr] = (double)a4.w;
        const float4 b4 = *(const float4*)&Wk[(size_t)(n0 + rr) * E + k0 + kI];
        Bs[kI + 0][rr] = (double)b4.x; Bs[kI + 1][rr] = (double)b4.y;
        Bs[kI + 2][rr] = (double)b4.z; Bs[kI + 3][rr] = (double)b4.w;
        __syncthreads();
#pragma unroll
        for (int k = 0; k < 16; ++k) {
            double av[4], bv[4];
#pragma unroll
            for (int i = 0; i < 4; ++i) av[i] = As[k][ty * 4 + i];
#pragma unroll
            for (int j = 0; j < 4; ++j) bv[j] = Bs[k][tx * 4 + j];
#pragma unroll
            for (int i = 0; i < 4; ++i)
#pragma unroll
                for (int j = 0; j < 4; ++j)
                    acc[i][j] = fma(av[i], bv[j], acc[i][j]);
        }
        __syncthreads();
    }

#pragma unroll
    for (int i = 0; i < 4; ++i)
#pragma unroll
        for (int j = 0; j < 4; ++j) {
            const double v = acc[i][j] + (double)bk[n0 + tx * 4 + j];
            K64 [(size_t)(m0 + ty * 4 + i) * E  + n0 + tx * 4 + j] = v;
            K64T[(size_t)(n0 + tx * 4 + j) * HH + m0 + ty * 4 + i] = v;
        }
}

// ---------------------------------------------------------------------------
// Kernel 2: S[h,k] = sum_e' K64[h,e'] * Wq[e',k] in fp32; epilogue emits bf16
// hi/lo split pair (Sh, Sl) for the MFMA fast path. Per-score error from this
// stage ~4e-4, far below MARGIN/2. Refine does not use S at all.
// ---------------------------------------------------------------------------
__global__ __launch_bounds__(256) void s_proj32_kernel(
    const double* __restrict__ K64, const float* __restrict__ Wq,
    unsigned short* __restrict__ Sh, unsigned short* __restrict__ Sl)
{
    __shared__ float As[32][68];   // [e'][h-row]
    __shared__ float Bs[32][68];   // [e'][k-col]

    const int t  = threadIdx.x;
    const int m0 = blockIdx.y * 64;   // h rows
    const int n0 = blockIdx.x * 64;   // k cols
    const int tx = t & 15, ty = t >> 4;

    const int ar  = t >> 2, aq = (t & 3) * 8;   // A: 8 doubles/thread
    const int bkk = t >> 3, bn = (t & 7) * 8;   // B: 8 floats/thread

    float acc[4][4] = {};

    for (int k0 = 0; k0 < E; k0 += 32) {
        {
            const double* ap = &K64[(size_t)(m0 + ar) * E + k0 + aq];
#pragma unroll
            for (int i = 0; i < 4; ++i) {
                const double2 d2 = *(const double2*)(ap + 2 * i);
                As[aq + 2 * i + 0][ar] = (float)d2.x;
                As[aq + 2 * i + 1][ar] = (float)d2.y;
            }
        }
        {
            const float4 b0 = *(const float4*)&Wq[(size_t)(k0 + bkk) * E + n0 + bn];
            const float4 b1 = *(const float4*)&Wq[(size_t)(k0 + bkk) * E + n0 + bn + 4];
            Bs[bkk][bn + 0] = b0.x; Bs[bkk][bn + 1] = b0.y;
            Bs[bkk][bn + 2] = b0.z; Bs[bkk][bn + 3] = b0.w;
            Bs[bkk][bn + 4] = b1.x; Bs[bkk][bn + 5] = b1.y;
            Bs[bkk][bn + 6] = b1.z; Bs[bkk][bn + 7] = b1.w;
        }
        __syncthreads();
#pragma unroll
        for (int k = 0; k < 32; ++k) {
            float av[4], bv[4];
#pragma unroll
            for (int i = 0; i < 4; ++i) av[i] = As[k][ty * 4 + i];
#pragma unroll
            for (int j = 0; j < 4; ++j) bv[j] = Bs[k][tx * 4 + j];
#pragma unroll
            for (int i = 0; i < 4; ++i)
#pragma unroll
                for (int j = 0; j < 4; ++j)
                    acc[i][j] = fmaf(av[i], bv[j], acc[i][j]);
        }
        __syncthreads();
    }

#pragma unroll
    for (int i = 0; i < 4; ++i) {
        const int h = m0 + ty * 4 + i;
        ushort4 h4, l4;
        float s;
        s = acc[i][0]; h4.x = f2bf(s); l4.x = f2bf(s - bf2f(h4.x));
        s = acc[i][1]; h4.y = f2bf(s); l4.y = f2bf(s - bf2f(h4.y));
        s = acc[i][2]; h4.z = f2bf(s); l4.z = f2bf(s - bf2f(h4.z));
        s = acc[i][3]; h4.w = f2bf(s); l4.w = f2bf(s - bf2f(h4.w));
        *(ushort4*)&Sh[(size_t)h * E + n0 + tx * 4] = h4;
        *(ushort4*)&Sl[(size_t)h * E + n0 + tx * 4] = l4;
    }
}

// ---------------------------------------------------------------------------
// Kernel 2b: c32[h] = dot(bq, K64[h,:]) (fp64 accum, fp32 out; fast path only;
// refine folds bq into Q instead)
// ---------------------------------------------------------------------------
__global__ __launch_bounds__(256) void cvec32_kernel(
    const float* __restrict__ bq, const double* __restrict__ K64,
    float* __restrict__ c32)
{
    const int h = blockIdx.x;
    const int t = threadIdx.x;
    double s = 0.0;
    for (int e = t; e < E; e += 256)
        s = fma((double)bq[e], K64[(size_t)h * E + e], s);
#pragma unroll
    for (int m = 32; m; m >>= 1) s += __shfl_down(s, m, 64);
    __shared__ double red[4];
    if ((t & 63) == 0) red[t >> 6] = s;
    __syncthreads();
    if (t == 0) c32[h] = (float)(red[0] + red[1] + red[2] + red[3]);
}

// ---------------------------------------------------------------------------
// Kernel 3: fast scores via bf16 hi/lo split MFMA + top-2 argmax + margin
// worklist. Block: 64 nodes x 256 hubs, 512 threads (8 waves, wave tile
// 32x64 = 2x4 frags of mfma_f32_16x16x32_bf16). (xh+xl)(sh+sl) ~
// hh + hl + lh; error ~5.5e-4 << MARGIN/2.
//
// DUPLICATE-HUB MASKING: sorted hub_indices contain ~2 duplicated values
// (birthday, 256 draws from 16384). Duplicate K rows are bitwise identical
// -> gap==0 -> without masking every node argmax'ing a duplicated hub
// (~64/hub) floods the worklist. bias[p] = -3.4e38 for later duplicates
// removes them from v1/v2 contention: v1 stays on the FIRST occurrence
// (same output value, np.argmax semantics preserved) and the margin is
// measured against the best genuinely-different hub value.
//
// LDS pitch 40 bf16 (80 B) keeps ds_read_b128 frags ~2-way (free, m136).
// ---------------------------------------------------------------------------
__global__ __launch_bounds__(512) void scores_mfma_kernel(
    const float* __restrict__ X,
    const unsigned short* __restrict__ Sh, const unsigned short* __restrict__ Sl,
    const float* __restrict__ c32, const int* __restrict__ hub,
    int* __restrict__ out, int* __restrict__ cnt, int* __restrict__ wl)
{
    __shared__ __align__(16) unsigned short Ah[64][40];
    __shared__ __align__(16) unsigned short Al[64][40];
    __shared__ __align__(16) unsigned short Bh[256][40];
    __shared__ __align__(16) unsigned short Bl[256][40];
    __shared__ float bias[256];
    __shared__ float mv1[4][64];
    __shared__ float mv2[4][64];
    __shared__ int   mi1[4][64];

    const int t    = threadIdx.x;
    const int m0   = blockIdx.x * 64;
    const int lane = t & 63;
    const int w    = t >> 6;
    const int wm   = w >> 2;      // node half   (0..1)
    const int wn   = w & 3;       // hub quarter (0..3)
    const int lr   = lane & 15;
    const int lg   = lane >> 4;

    const int arow = t >> 3;          // A staging: 0..63
    const int akc  = (t & 7) * 4;     // 0..28

    // per-hub bias: c-vector, with later duplicates masked to -inf
    if (t < 256) {
        const bool dup = (t > 0) && (hub[t - 1] == hub[t]);
        bias[t] = dup ? -3.4e38f : c32[t];
    }

    f32x4 acc[2][4] = {};

    for (int k0 = 0; k0 < E; k0 += 32) {
        // stage A: X tile 64x32 fp32 -> bf16 hi/lo
        {
            const float4 a4 = *(const float4*)&X[(size_t)(m0 + arow) * E + k0 + akc];
            ushort4 h4, l4;
            h4.x = f2bf(a4.x); l4.x = f2bf(a4.x - bf2f(h4.x));
            h4.y = f2bf(a4.y); l4.y = f2bf(a4.y - bf2f(h4.y));
            h4.z = f2bf(a4.z); l4.z = f2bf(a4.z - bf2f(h4.z));
            h4.w = f2bf(a4.w); l4.w = f2bf(a4.w - bf2f(h4.w));
            *(ushort4*)&Ah[arow][akc] = h4;
            *(ushort4*)&Al[arow][akc] = l4;
        }
        // stage B: Sh/Sl tiles 256x32 bf16 (16B chunks, coalesced)
#pragma unroll
        for (int rep = 0; rep < 2; ++rep) {
            const int c   = t + rep * 512;
            const int row = c >> 2;
            const int kq  = (c & 3) * 8;
            *(uint4*)&Bh[row][kq] = *(const uint4*)&Sh[(size_t)row * E + k0 + kq];
            *(uint4*)&Bl[row][kq] = *(const uint4*)&Sl[(size_t)row * E + k0 + kq];
        }
        __syncthreads();

        bf16x8 a_h[2], a_l[2], b_h[4], b_l[4];
#pragma unroll
        for (int im = 0; im < 2; ++im) {
            const int row = wm * 32 + im * 16 + lr;
            a_h[im] = *(const bf16x8*)&Ah[row][lg * 8];
            a_l[im] = *(const bf16x8*)&Al[row][lg * 8];
        }
#pragma unroll
        for (int in = 0; in < 4; ++in) {
            const int row = wn * 64 + in * 16 + lr;
            b_h[in] = *(const bf16x8*)&Bh[row][lg * 8];
            b_l[in] = *(const bf16x8*)&Bl[row][lg * 8];
        }
        // product-major order spaces the dependent C-chains 8 apart
#pragma unroll
        for (int im = 0; im < 2; ++im)
#pragma unroll
            for (int in = 0; in < 4; ++in)
                acc[im][in] = __builtin_amdgcn_mfma_f32_16x16x32_bf16(
                    a_h[im], b_h[in], acc[im][in], 0, 0, 0);
#pragma unroll
        for (int im = 0; im < 2; ++im)
#pragma unroll
            for (int in = 0; in < 4; ++in)
                acc[im][in] = __builtin_amdgcn_mfma_f32_16x16x32_bf16(
                    a_h[im], b_l[in], acc[im][in], 0, 0, 0);
#pragma unroll
        for (int im = 0; im < 2; ++im)
#pragma unroll
            for (int in = 0; in < 4; ++in)
                acc[im][in] = __builtin_amdgcn_mfma_f32_16x16x32_bf16(
                    a_l[im], b_h[in], acc[im][in], 0, 0, 0);
        __syncthreads();
    }

    // epilogue: add bias, top-2 per node, cross-wave merge, margin worklist.
    // D layout (16x16x32): col = lane&15 (hub), row = (lane>>4)*4 + reg (node).
    float cr[4];
#pragma unroll
    for (int in = 0; in < 4; ++in) cr[in] = bias[wn * 64 + in * 16 + lr];

#pragma unroll
    for (int im = 0; im < 2; ++im) {
#pragma unroll
        for (int r = 0; r < 4; ++r) {
            float v1 = -3.4e38f, v2 = -3.4e38f;
            int   i1 = 0;
#pragma unroll
            for (int in = 0; in < 4; ++in) {   // ascending hub position
                const float v = acc[im][in][r] + cr[in];
                if (v > v1)      { v2 = v1; v1 = v; i1 = wn * 64 + in * 16 + lr; }
                else if (v > v2) { v2 = v; }
            }
            // butterfly over the 16 lr-lanes (masks <16 stay in the lg-group)
#pragma unroll
            for (int m = 8; m; m >>= 1) {
                const float ov1 = __shfl_xor(v1, m, 64);
                const int   oi1 = __shfl_xor(i1, m, 64);
                const float ov2 = __shfl_xor(v2, m, 64);
                if (ov1 > v1 || (ov1 == v1 && oi1 < i1)) {
                    v2 = fmaxf(v1, ov2); v1 = ov1; i1 = oi1;
                } else {
                    v2 = fmaxf(v2, ov1);
                }
            }
            if (lr == 0) {
                const int nl = wm * 32 + im * 16 + lg * 4 + r;
                mv1[wn][nl] = v1; mi1[wn][nl] = i1; mv2[wn][nl] = v2;
            }
        }
    }
    __syncthreads();

    if (t < 64) {
        float v1 = -3.4e38f, v2 = -3.4e38f;
        int   i1 = 0x7fffffff;
#pragma unroll
        for (int wq = 0; wq < 4; ++wq) {
            const float a1 = mv1[wq][t];
            const int   ai = mi1[wq][t];
            const float a2 = mv2[wq][t];
            if (a1 > v1 || (a1 == v1 && ai < i1)) {
                v2 = fmaxf(v2, v1); v1 = a1; i1 = ai; v2 = fmaxf(v2, a2);
            } else {
                v2 = fmaxf(v2, a1);
            }
        }
        const int node = m0 + t;
        out[node] = hub[i1];
        if (v1 - v2 < MARGIN) {
            const int idx = atomicAdd(cnt, 1);
            if (idx < WL_CAP) wl[idx] = node;
        }
    }
}

// ---------------------------------------------------------------------------
// Kernel 4a: refine stage Q — Q64[slot,e'] = sum_k X[wl[slot],k]*Wq[e',k]
// + bq[e'] in exact fp64. Tile 16 slots x 64 e'-cols; grid (64, 16) with
// early exit (expected ~2 active y-slices at ~30 worklist nodes).
// ---------------------------------------------------------------------------
__global__ __launch_bounds__(256) void refine_q_kernel(
    const float* __restrict__ X, const float* __restrict__ Wq,
    const float* __restrict__ bq, const int* __restrict__ cnt,
    const int* __restrict__ wl, double* __restrict__ Q64)
{
    const int n = min(min(*cnt, WL_CAP), REF_SLOTS);
    const int slot0 = blockIdx.y * QT;
    if (slot0 >= n) return;
    const int ep0 = blockIdx.x * 64;
    const int t = threadIdx.x;

    __shared__ int rows[QT];
    __shared__ float As[32][QT + 4];   // [k][slot-row]
    __shared__ float Bs[32][68];       // [k][e'-col]
    if (t < QT) rows[t] = wl[min(slot0 + t, n - 1)];  // clamp: duplicate work, always valid
    __syncthreads();

    const int r  = t >> 4;         // slot-row 0..15
    const int cg = (t & 15) * 4;   // e' col group

    double acc[4] = {0.0, 0.0, 0.0, 0.0};

    for (int k0 = 0; k0 < E; k0 += 32) {
        if (t < 128) {
            const int ar = t >> 3, kc = (t & 7) * 4;
            const float4 a4 = *(const float4*)&X[(size_t)rows[ar] * E + k0 + kc];
            As[kc + 0][ar] = a4.x; As[kc + 1][ar] = a4.y;
            As[kc + 2][ar] = a4.z; As[kc + 3][ar] = a4.w;
        }
        {
            const int br = t >> 2, kc = (t & 3) * 8;
            const float4 b0 = *(const float4*)&Wq[(size_t)(ep0 + br) * E + k0 + kc];
            const float4 b1 = *(const float4*)&Wq[(size_t)(ep0 + br) * E + k0 + kc + 4];
            Bs[kc + 0][br] = b0.x; Bs[kc + 1][br] = b0.y;
            Bs[kc + 2][br] = b0.z; Bs[kc + 3][br] = b0.w;
            Bs[kc + 4][br] = b1.x; Bs[kc + 5][br] = b1.y;
            Bs[kc + 6][br] = b1.z; Bs[kc + 7][br] = b1.w;
        }
        __syncthreads();
#pragma unroll
        for (int k = 0; k < 32; ++k) {
            const double a = (double)As[k][r];
#pragma unroll
            for (int j = 0; j < 4; ++j)
                acc[j] = fma(a, (double)Bs[k][cg + j], acc[j]);
        }
        __syncthreads();
    }
#pragma unroll
    for (int j = 0; j < 4; ++j)
        Q64[(size_t)(slot0 + r) * E + ep0 + cg + j] = acc[j] + (double)bq[ep0 + cg + j];
}

// ---------------------------------------------------------------------------
// Kernel 4b: refine partial dots — partial[slot,c,h] over e'-chunk c.
// Thread t owns hub t; K64T reads coalesced (2 KB per e'-row).
// ---------------------------------------------------------------------------
__global__ __launch_bounds__(256) void refine_partial_kernel(
    const double* __restrict__ Q64, const double* __restrict__ K64T,
    const int* __restrict__ cnt, const int* __restrict__ wl,
    double* __restrict__ partials)
{
    const int slot = blockIdx.y;
    const int n = min(min(*cnt, WL_CAP), REF_SLOTS);
    if (slot >= n) return;

    const int t  = threadIdx.x;
    const int c  = blockIdx.x;      // e'-chunk 0..7
    const int e0 = c * 512;

    __shared__ __align__(16) double Qs[512];
    if (t < 128) {
        const double2 q0 = *(const double2*)&Q64[(size_t)slot * E + e0 + t * 4];
        const double2 q1 = *(const double2*)&Q64[(size_t)slot * E + e0 + t * 4 + 2];
        Qs[t * 4 + 0] = q0.x; Qs[t * 4 + 1] = q0.y;
        Qs[t * 4 + 2] = q1.x; Qs[t * 4 + 3] = q1.y;
    }
    __syncthreads();

    double a0 = 0, a1 = 0, a2 = 0, a3 = 0;
    for (int e = 0; e < 512; e += 4) {
        const size_t base = (size_t)(e0 + e) * HH + t;
        a0 = fma(Qs[e + 0], K64T[base + 0 * HH], a0);
        a1 = fma(Qs[e + 1], K64T[base + 1 * HH], a1);
        a2 = fma(Qs[e + 2], K64T[base + 2 * HH], a2);
        a3 = fma(Qs[e + 3], K64T[base + 3 * HH], a3);
    }
    partials[((size_t)slot * 8 + c) * HH + t] = (a0 + a1) + (a2 + a3);
}

// ---------------------------------------------------------------------------
// Kernel 4c: combine chunk-partials, block argmax (first-max, tie -> lower
// hub position, matching np.argmax). bq already folded into Q64.
// ---------------------------------------------------------------------------
__global__ __launch_bounds__(256) void refine_reduce_kernel(
    const double* __restrict__ partials, const int* __restrict__ hub,
    const int* __restrict__ cnt, const int* __restrict__ wl,
    int* __restrict__ out)
{
    const int slot = blockIdx.x;
    const int n = min(min(*cnt, WL_CAP), REF_SLOTS);
    if (slot >= n) return;

    const int t = threadIdx.x;
    double v = 0.0;
#pragma unroll
    for (int c = 0; c < 8; ++c)
        v += partials[((size_t)slot * 8 + c) * HH + t];

    __shared__ double rv[256];
    __shared__ int    ri[256];
    rv[t] = v; ri[t] = t;
    __syncthreads();
    for (int s = 128; s; s >>= 1) {
        if (t < s) {
            const bool better = rv[t + s] > rv[t] ||
                                (rv[t + s] == rv[t] && ri[t + s] < ri[t]);
            if (better) { rv[t] = rv[t + s]; ri[t] = ri[t + s]; }
        }
        __syncthreads();
    }
    if (t == 0) out[wl[slot]] = hub[ri[0]];
}

// ---------------------------------------------------------------------------
// Kernel 5: hub nodes map to themselves (isin override). Must run LAST.
// ---------------------------------------------------------------------------
__global__ void hub_override_kernel(const int* __restrict__ hub,
                                    int* __restrict__ out)
{
    const int t = threadIdx.x;
    if (t < HH) { const int h = hub[t]; out[h] = h; }
}

extern "C" void kernel_launch(void* const* d_in, const int* in_sizes, int n_in,
                              void* d_out, int out_size, void* d_ws, size_t ws_size,
                              hipStream_t stream) {
    const float* X   = (const float*)d_in[0];   // [NN, E]
    const int*   hub = (const int*)  d_in[1];   // [HH]
    const float* Wq  = (const float*)d_in[2];   // [E, E]
    const float* bq  = (const float*)d_in[3];   // [E]
    const float* Wk  = (const float*)d_in[4];   // [E, E]
    const float* bk  = (const float*)d_in[5];   // [E]
    int* out = (int*)d_out;                     // [NN]

    // workspace (~20.0 MB):
    //   K64  [HH][E] d  8 MB   (dead after cvec32 -> Q64 aliases it)
    //   K64T [E][HH] d  8 MB   (live through refine)
    //   Sh,Sl [HH][E] bf16 2+2 MB (dead after scores -> partials alias)
    //   c32, cnt, wl            ~9 KB
    double*         K64  = (double*)d_ws;
    double*         K64T = K64 + (size_t)HH * E;
    unsigned short* Sh   = (unsigned short*)(K64T + (size_t)HH * E);
    unsigned short* Sl   = Sh + (size_t)HH * E;
    float*          c32  = (float*)(Sl + (size_t)HH * E);
    int*            cnt  = (int*)(c32 + HH);
    int*            wl   = cnt + 1;                 // [WL_CAP]
    double*         Q64  = K64;                     // [REF_SLOTS][E]    8 MB alias
    double*         partials = (double*)Sh;         // [REF_SLOTS][8][HH] 4 MB alias

    init_kernel<<<dim3(1), 64, 0, stream>>>(cnt);
    k_proj64_kernel<<<dim3(E / 64, HH / 64), 256, 0, stream>>>(X, hub, Wk, bk, K64, K64T);
    s_proj32_kernel<<<dim3(E / 64, HH / 64), 256, 0, stream>>>(K64, Wq, Sh, Sl);
    cvec32_kernel<<<dim3(HH), 256, 0, stream>>>(bq, K64, c32);
    scores_mfma_kernel<<<dim3(NN / 64), 512, 0, stream>>>(X, Sh, Sl, c32, hub, out, cnt, wl);
    refine_q_kernel<<<dim3(E / 64, REF_SLOTS / QT), 256, 0, stream>>>(X, Wq, bq, cnt, wl, Q64);
    refine_partial_kernel<<<dim3(8, REF_SLOTS), 256, 0, stream>>>(Q64, K64T, cnt, wl, partials);
    refine_reduce_kernel<<<dim3(REF_SLOTS), 256, 0, stream>>>(partials, hub, cnt, wl, out);
    hub_override_kernel<<<dim3(1), 256, 0, stream>>>(hub, out);
}

// Round 6
// 1336.346 us; speedup vs baseline: 1.1507x; 1.1507x over previous
//
#include <hip/hip_runtime.h>

#define E  4096
#define NN 16384
#define HH 256
#define WL_CAP 2048
#define REF_SLOTS 256
#define QT 16
#define MARGIN 0.0625f

typedef __attribute__((ext_vector_type(4))) float  f32x4;
typedef __attribute__((ext_vector_type(8))) short  bf16x8;

// round-to-nearest-even fp32 -> bf16 (inputs are finite Gaussians; no NaN path)
static __device__ __forceinline__ unsigned short f2bf(float f) {
    unsigned int u = __float_as_uint(f);
    u += 0x7fffu + ((u >> 16) & 1u);
    return (unsigned short)(u >> 16);
}
static __device__ __forceinline__ float bf2f(unsigned short h) {
    return __uint_as_float((unsigned int)h << 16);
}

// ---------------------------------------------------------------------------
// init: zero the refine-worklist counter (ws is poisoned 0xAA every call)
// ---------------------------------------------------------------------------
__global__ void init_kernel(int* cnt) { if (threadIdx.x == 0) *cnt = 0; }

// ---------------------------------------------------------------------------
// Kernel 1 (fallback, VERIFIED in Round 2): K64[h,e] = sum_k X[hub[h],k] *
// Wk[e,k] + bk[e], fp64 accum, single pass. Used only when ws_size can't
// hold k-split partials. Deterministic per-row order => duplicate hub rows
// bitwise identical.
// ---------------------------------------------------------------------------
__global__ __launch_bounds__(256) void k_proj64_kernel(
    const float* __restrict__ X, const int* __restrict__ hub,
    const float* __restrict__ Wk, const float* __restrict__ bk,
    double* __restrict__ K64, double* __restrict__ K64T)
{
    __shared__ double As[16][68];
    __shared__ double Bs[16][68];
    __shared__ int rows[64];

    const int t  = threadIdx.x;
    const int m0 = blockIdx.y * 64;   // hub rows
    const int n0 = blockIdx.x * 64;   // e cols

    if (t < 64) rows[t] = hub[m0 + t];
    __syncthreads();

    const int tx = t & 15, ty = t >> 4;
    const int kI = (t & 3) * 4, rr = t >> 2;   // rr 0..63

    double acc[4][4] = {};

    for (int k0 = 0; k0 < E; k0 += 16) {
        const float4 a4 = *(const float4*)&X[(size_t)rows[rr] * E + k0 + kI];
        As[kI + 0][rr] = (double)a4.x; As[kI + 1][rr] = (double)a4.y;
        As[kI + 2][rr] = (double)a4.z; As[kI + 3][rr] = (double)a4.w;
        const float4 b4 = *(const float4*)&Wk[(size_t)(n0 + rr) * E + k0 + kI];
        Bs[kI + 0][rr] = (double)b4.x; Bs[kI + 1][rr] = (double)b4.y;
        Bs[kI + 2][rr] = (double)b4.z; Bs[kI + 3][rr] = (double)b4.w;
        __syncthreads();
#pragma unroll
        for (int k = 0; k < 16; ++k) {
            double av[4], bv[4];
#pragma unroll
            for (int i = 0; i < 4; ++i) av[i] = As[k][ty * 4 + i];
#pragma unroll
            for (int j = 0; j < 4; ++j) bv[j] = Bs[k][tx * 4 + j];
#pragma unroll
            for (int i = 0; i < 4; ++i)
#pragma unroll
                for (int j = 0; j < 4; ++j)
                    acc[i][j] = fma(av[i], bv[j], acc[i][j]);
        }
        __syncthreads();
    }

#pragma unroll
    for (int i = 0; i < 4; ++i)
#pragma unroll
        for (int j = 0; j < 4; ++j) {
            const double v = acc[i][j] + (double)bk[n0 + tx * 4 + j];
            K64 [(size_t)(m0 + ty * 4 + i) * E  + n0 + tx * 4 + j] = v;
            K64T[(size_t)(n0 + tx * 4 + j) * HH + m0 + ty * 4 + i] = v;
        }
}

// ---------------------------------------------------------------------------
// Kernel 1a: k-split partial. IDENTICAL math to k_proj64 over k-slice
// [z*kspan, (z+1)*kspan); writes partials[z][h][e], no bk. Round-2 counters
// showed k_proj64 at Occupancy 11.7% (grid 256 = 1 blk/CU, the grid is the
// limiter), VALUBusy 25.8%, HBM 1.8% -> latency-bound. KS=8 -> 2048 blocks
// = 8 blk/CU (LDS 17.7KB x 8 = 141KB < 160KB, full 32 waves/CU).
// Per-row summation order fixed => duplicate hub rows bitwise identical.
// (f64 MFMA was tried in Round 3 and produced the within-16-group row
// permutation signature — its D-layout is NOT the verified bf16 mapping.
// Stay on verified VALU math; fix occupancy instead.)
// ---------------------------------------------------------------------------
__global__ __launch_bounds__(256) void k_proj_part_kernel(
    const float* __restrict__ X, const int* __restrict__ hub,
    const float* __restrict__ Wk, int kspan, double* __restrict__ part)
{
    __shared__ double As[16][68];
    __shared__ double Bs[16][68];
    __shared__ int rows[64];

    const int t  = threadIdx.x;
    const int m0 = blockIdx.y * 64;   // hub rows
    const int n0 = blockIdx.x * 64;   // e cols
    const int kbeg = blockIdx.z * kspan;

    if (t < 64) rows[t] = hub[m0 + t];
    __syncthreads();

    const int tx = t & 15, ty = t >> 4;
    const int kI = (t & 3) * 4, rr = t >> 2;

    double acc[4][4] = {};

    for (int k0 = kbeg; k0 < kbeg + kspan; k0 += 16) {
        const float4 a4 = *(const float4*)&X[(size_t)rows[rr] * E + k0 + kI];
        As[kI + 0][rr] = (double)a4.x; As[kI + 1][rr] = (double)a4.y;
        As[kI + 2][rr] = (double)a4.z; As[kI + 3][rr] = (double)a4.w;
        const float4 b4 = *(const float4*)&Wk[(size_t)(n0 + rr) * E + k0 + kI];
        Bs[kI + 0][rr] = (double)b4.x; Bs[kI + 1][rr] = (double)b4.y;
        Bs[kI + 2][rr] = (double)b4.z; Bs[kI + 3][rr] = (double)b4.w;
        __syncthreads();
#pragma unroll
        for (int k = 0; k < 16; ++k) {
            double av[4], bv[4];
#pragma unroll
            for (int i = 0; i < 4; ++i) av[i] = As[k][ty * 4 + i];
#pragma unroll
            for (int j = 0; j < 4; ++j) bv[j] = Bs[k][tx * 4 + j];
#pragma unroll
            for (int i = 0; i < 4; ++i)
#pragma unroll
                for (int j = 0; j < 4; ++j)
                    acc[i][j] = fma(av[i], bv[j], acc[i][j]);
        }
        __syncthreads();
    }

#pragma unroll
    for (int i = 0; i < 4; ++i)
#pragma unroll
        for (int j = 0; j < 4; ++j)
            part[(size_t)blockIdx.z * HH * E +
                 (size_t)(m0 + ty * 4 + i) * E + n0 + tx * 4 + j] = acc[i][j];
}

// ---------------------------------------------------------------------------
// Kernel 1b: fixed-order reduce of k-split partials (+bk), writes K64 and
// K64T (coalesced via LDS 64x64 tile transpose). Deterministic: z ascending,
// bk added last -> duplicate hub rows stay bitwise identical.
// ---------------------------------------------------------------------------
__global__ __launch_bounds__(256) void k_reduce_kernel(
    const double* __restrict__ part, const float* __restrict__ bk,
    int ks, double* __restrict__ K64, double* __restrict__ K64T)
{
    __shared__ double tile[64][65];
    const int t  = threadIdx.x;
    const int e0 = blockIdx.x * 64, h0 = blockIdx.y * 64;

#pragma unroll
    for (int rep = 0; rep < 16; ++rep) {
        const int idx = rep * 256 + t;
        const int lh = idx >> 6, le = idx & 63;
        const size_t off = (size_t)(h0 + lh) * E + e0 + le;
        double s = part[off];
        for (int z = 1; z < ks; ++z) s += part[(size_t)z * HH * E + off];
        const double v = s + (double)bk[e0 + le];
        K64[off] = v;
        tile[lh][le] = v;
    }
    __syncthreads();
#pragma unroll
    for (int rep = 0; rep < 16; ++rep) {
        const int idx = rep * 256 + t;
        const int le = idx >> 6, lh = idx & 63;
        K64T[(size_t)(e0 + le) * HH + h0 + lh] = tile[lh][le];
    }
}

// ---------------------------------------------------------------------------
// Kernel 2: S[h,k] = sum_k' K64[h,k'] * Wq[k',k] via 3-term bf16-split MFMA
// (hh+hl+lh). Re-audited: all frag mappings mirror the Round-2-VERIFIED
// scores_mfma patterns; absmax-1152 signature matches the f64-MFMA row
// permutation, not this kernel. Epilogue emits Sh/Sl bf16 hi/lo pair.
// ---------------------------------------------------------------------------
__global__ __launch_bounds__(256) void s_proj_mfma_kernel(
    const double* __restrict__ K64, const float* __restrict__ Wq,
    unsigned short* __restrict__ Sh, unsigned short* __restrict__ Sl)
{
    __shared__ __align__(16) unsigned short Ah[64][40];  // [h][k'] bf16 hi
    __shared__ __align__(16) unsigned short Al[64][40];  // [h][k'] bf16 lo
    __shared__ __align__(16) float Bf[32][72];           // [k'][k-col] f32

    const int t  = threadIdx.x;
    const int m0 = blockIdx.y * 64;   // h rows
    const int n0 = blockIdx.x * 64;   // k cols

    const int lane = t & 63;
    const int w    = t >> 6;
    const int wr   = w >> 1;        // h half
    const int wc   = w & 1;         // k half
    const int lr   = lane & 15;
    const int lg   = lane >> 4;

    const int arow = t >> 2;          // A staging: h row 0..63
    const int akc  = (t & 3) * 8;     // k' 0,8,16,24
    const int bkr  = t >> 3;          // B staging: k' row 0..31
    const int bnc  = (t & 7) * 8;     // k col 0..56

    f32x4 acc[2][2] = {};

    for (int k0 = 0; k0 < E; k0 += 32) {
        // stage A: K64 64x32 fp64 -> float -> bf16 hi/lo
        {
            const double* ap = &K64[(size_t)(m0 + arow) * E + k0 + akc];
#pragma unroll
            for (int q = 0; q < 2; ++q) {
                const double2 d0 = *(const double2*)(ap + 4 * q);
                const double2 d1 = *(const double2*)(ap + 4 * q + 2);
                const float f0 = (float)d0.x, f1 = (float)d0.y;
                const float f2 = (float)d1.x, f3 = (float)d1.y;
                ushort4 hh, ll;
                hh.x = f2bf(f0); ll.x = f2bf(f0 - bf2f(hh.x));
                hh.y = f2bf(f1); ll.y = f2bf(f1 - bf2f(hh.y));
                hh.z = f2bf(f2); ll.z = f2bf(f2 - bf2f(hh.z));
                hh.w = f2bf(f3); ll.w = f2bf(f3 - bf2f(hh.w));
                *(ushort4*)&Ah[arow][akc + 4 * q] = hh;
                *(ushort4*)&Al[arow][akc + 4 * q] = ll;
            }
        }
        // stage B: Wq 32x64 f32, contiguous rows
        {
            const float* wp = &Wq[(size_t)(k0 + bkr) * E + n0 + bnc];
            *(float4*)&Bf[bkr][bnc]     = *(const float4*)wp;
            *(float4*)&Bf[bkr][bnc + 4] = *(const float4*)(wp + 4);
        }
        __syncthreads();

        bf16x8 a_h[2], a_l[2], b_h[2], b_l[2];
#pragma unroll
        for (int im = 0; im < 2; ++im) {
            const int row = wr * 32 + im * 16 + lr;
            a_h[im] = *(const bf16x8*)&Ah[row][lg * 8];
            a_l[im] = *(const bf16x8*)&Al[row][lg * 8];
        }
#pragma unroll
        for (int in = 0; in < 2; ++in) {
            const int col = wc * 32 + in * 16 + lr;
#pragma unroll
            for (int j = 0; j < 8; ++j) {
                const float f = Bf[lg * 8 + j][col];   // column read (transpose)
                const unsigned short bh = f2bf(f);
                b_h[in][j] = (short)bh;
                b_l[in][j] = (short)f2bf(f - bf2f(bh));
            }
        }
#pragma unroll
        for (int im = 0; im < 2; ++im)
#pragma unroll
            for (int in = 0; in < 2; ++in)
                acc[im][in] = __builtin_amdgcn_mfma_f32_16x16x32_bf16(
                    a_h[im], b_h[in], acc[im][in], 0, 0, 0);
#pragma unroll
        for (int im = 0; im < 2; ++im)
#pragma unroll
            for (int in = 0; in < 2; ++in)
                acc[im][in] = __builtin_amdgcn_mfma_f32_16x16x32_bf16(
                    a_h[im], b_l[in], acc[im][in], 0, 0, 0);
#pragma unroll
        for (int im = 0; im < 2; ++im)
#pragma unroll
            for (int in = 0; in < 2; ++in)
                acc[im][in] = __builtin_amdgcn_mfma_f32_16x16x32_bf16(
                    a_l[im], b_h[in], acc[im][in], 0, 0, 0);
        __syncthreads();
    }

    // D layout: col = lane&15 (k), row = (lane>>4)*4 + reg (h)
#pragma unroll
    for (int im = 0; im < 2; ++im)
#pragma unroll
        for (int in = 0; in < 2; ++in) {
            const int kc = n0 + wc * 32 + in * 16 + lr;
#pragma unroll
            for (int r = 0; r < 4; ++r) {
                const int h = m0 + wr * 32 + im * 16 + 4 * lg + r;
                const float s = acc[im][in][r];
                const unsigned short sh = f2bf(s);
                Sh[(size_t)h * E + kc] = sh;
                Sl[(size_t)h * E + kc] = f2bf(s - bf2f(sh));
            }
        }
}

// ---------------------------------------------------------------------------
// Kernel 2b: c32[h] = dot(bq, K64[h,:]) (fp64 accum, fp32 out; fast path only;
// refine folds bq into Q instead)
// ---------------------------------------------------------------------------
__global__ __launch_bounds__(256) void cvec32_kernel(
    const float* __restrict__ bq, const double* __restrict__ K64,
    float* __restrict__ c32)
{
    const int h = blockIdx.x;
    const int t = threadIdx.x;
    double s = 0.0;
    for (int e = t; e < E; e += 256)
        s = fma((double)bq[e], K64[(size_t)h * E + e], s);
#pragma unroll
    for (int m = 32; m; m >>= 1) s += __shfl_down(s, m, 64);
    __shared__ double red[4];
    if ((t & 63) == 0) red[t >> 6] = s;
    __syncthreads();
    if (t == 0) c32[h] = (float)(red[0] + red[1] + red[2] + red[3]);
}

// ---------------------------------------------------------------------------
// Kernel 3: fast scores via bf16 hi/lo split MFMA + top-2 argmax + margin
// worklist (VERIFIED Round 2). 64 nodes x 256 hubs, 512 threads.
// Duplicate-hub masking: later duplicates biased to -inf (see Round-1 note).
// ---------------------------------------------------------------------------
__global__ __launch_bounds__(512) void scores_mfma_kernel(
    const float* __restrict__ X,
    const unsigned short* __restrict__ Sh, const unsigned short* __restrict__ Sl,
    const float* __restrict__ c32, const int* __restrict__ hub,
    int* __restrict__ out, int* __restrict__ cnt, int* __restrict__ wl)
{
    __shared__ __align__(16) unsigned short Ah[64][40];
    __shared__ __align__(16) unsigned short Al[64][40];
    __shared__ __align__(16) unsigned short Bh[256][40];
    __shared__ __align__(16) unsigned short Bl[256][40];
    __shared__ float bias[256];
    __shared__ float mv1[4][64];
    __shared__ float mv2[4][64];
    __shared__ int   mi1[4][64];

    const int t    = threadIdx.x;
    const int m0   = blockIdx.x * 64;
    const int lane = t & 63;
    const int w    = t >> 6;
    const int wm   = w >> 2;      // node half   (0..1)
    const int wn   = w & 3;       // hub quarter (0..3)
    const int lr   = lane & 15;
    const int lg   = lane >> 4;

    const int arow = t >> 3;          // A staging: 0..63
    const int akc  = (t & 7) * 4;     // 0..28

    // per-hub bias: c-vector, with later duplicates masked to -inf
    if (t < 256) {
        const bool dup = (t > 0) && (hub[t - 1] == hub[t]);
        bias[t] = dup ? -3.4e38f : c32[t];
    }

    f32x4 acc[2][4] = {};

    for (int k0 = 0; k0 < E; k0 += 32) {
        // stage A: X tile 64x32 fp32 -> bf16 hi/lo
        {
            const float4 a4 = *(const float4*)&X[(size_t)(m0 + arow) * E + k0 + akc];
            ushort4 h4, l4;
            h4.x = f2bf(a4.x); l4.x = f2bf(a4.x - bf2f(h4.x));
            h4.y = f2bf(a4.y); l4.y = f2bf(a4.y - bf2f(h4.y));
            h4.z = f2bf(a4.z); l4.z = f2bf(a4.z - bf2f(h4.z));
            h4.w = f2bf(a4.w); l4.w = f2bf(a4.w - bf2f(h4.w));
            *(ushort4*)&Ah[arow][akc] = h4;
            *(ushort4*)&Al[arow][akc] = l4;
        }
        // stage B: Sh/Sl tiles 256x32 bf16 (16B chunks, coalesced)
#pragma unroll
        for (int rep = 0; rep < 2; ++rep) {
            const int c   = t + rep * 512;
            const int row = c >> 2;
            const int kq  = (c & 3) * 8;
            *(uint4*)&Bh[row][kq] = *(const uint4*)&Sh[(size_t)row * E + k0 + kq];
            *(uint4*)&Bl[row][kq] = *(const uint4*)&Sl[(size_t)row * E + k0 + kq];
        }
        __syncthreads();

        bf16x8 a_h[2], a_l[2], b_h[4], b_l[4];
#pragma unroll
        for (int im = 0; im < 2; ++im) {
            const int row = wm * 32 + im * 16 + lr;
            a_h[im] = *(const bf16x8*)&Ah[row][lg * 8];
            a_l[im] = *(const bf16x8*)&Al[row][lg * 8];
        }
#pragma unroll
        for (int in = 0; in < 4; ++in) {
            const int row = wn * 64 + in * 16 + lr;
            b_h[in] = *(const bf16x8*)&Bh[row][lg * 8];
            b_l[in] = *(const bf16x8*)&Bl[row][lg * 8];
        }
        // product-major order spaces the dependent C-chains 8 apart
#pragma unroll
        for (int im = 0; im < 2; ++im)
#pragma unroll
            for (int in = 0; in < 4; ++in)
                acc[im][in] = __builtin_amdgcn_mfma_f32_16x16x32_bf16(
                    a_h[im], b_h[in], acc[im][in], 0, 0, 0);
#pragma unroll
        for (int im = 0; im < 2; ++im)
#pragma unroll
            for (int in = 0; in < 4; ++in)
                acc[im][in] = __builtin_amdgcn_mfma_f32_16x16x32_bf16(
                    a_h[im], b_l[in], acc[im][in], 0, 0, 0);
#pragma unroll
        for (int im = 0; im < 2; ++im)
#pragma unroll
            for (int in = 0; in < 4; ++in)
                acc[im][in] = __builtin_amdgcn_mfma_f32_16x16x32_bf16(
                    a_l[im], b_h[in], acc[im][in], 0, 0, 0);
        __syncthreads();
    }

    // epilogue: add bias, top-2 per node, cross-wave merge, margin worklist.
    // D layout (16x16x32): col = lane&15 (hub), row = (lane>>4)*4 + reg (node).
    float cr[4];
#pragma unroll
    for (int in = 0; in < 4; ++in) cr[in] = bias[wn * 64 + in * 16 + lr];

#pragma unroll
    for (int im = 0; im < 2; ++im) {
#pragma unroll
        for (int r = 0; r < 4; ++r) {
            float v1 = -3.4e38f, v2 = -3.4e38f;
            int   i1 = 0;
#pragma unroll
            for (int in = 0; in < 4; ++in) {   // ascending hub position
                const float v = acc[im][in][r] + cr[in];
                if (v > v1)      { v2 = v1; v1 = v; i1 = wn * 64 + in * 16 + lr; }
                else if (v > v2) { v2 = v; }
            }
            // butterfly over the 16 lr-lanes (masks <16 stay in the lg-group)
#pragma unroll
            for (int m = 8; m; m >>= 1) {
                const float ov1 = __shfl_xor(v1, m, 64);
                const int   oi1 = __shfl_xor(i1, m, 64);
                const float ov2 = __shfl_xor(v2, m, 64);
                if (ov1 > v1 || (ov1 == v1 && oi1 < i1)) {
                    v2 = fmaxf(v1, ov2); v1 = ov1; i1 = oi1;
                } else {
                    v2 = fmaxf(v2, ov1);
                }
            }
            if (lr == 0) {
                const int nl = wm * 32 + im * 16 + lg * 4 + r;
                mv1[wn][nl] = v1; mi1[wn][nl] = i1; mv2[wn][nl] = v2;
            }
        }
    }
    __syncthreads();

    if (t < 64) {
        float v1 = -3.4e38f, v2 = -3.4e38f;
        int   i1 = 0x7fffffff;
#pragma unroll
        for (int wq = 0; wq < 4; ++wq) {
            const float a1 = mv1[wq][t];
            const int   ai = mi1[wq][t];
            const float a2 = mv2[wq][t];
            if (a1 > v1 || (a1 == v1 && ai < i1)) {
                v2 = fmaxf(v2, v1); v1 = a1; i1 = ai; v2 = fmaxf(v2, a2);
            } else {
                v2 = fmaxf(v2, a1);
            }
        }
        const int node = m0 + t;
        out[node] = hub[i1];
        if (v1 - v2 < MARGIN) {
            const int idx = atomicAdd(cnt, 1);
            if (idx < WL_CAP) wl[idx] = node;
        }
    }
}

// ---------------------------------------------------------------------------
// Kernel 4a: refine stage Q — Q64[slot,e'] = sum_k X[wl[slot],k]*Wq[e',k]
// + bq[e'] in exact fp64 (VERIFIED Round 2).
// ---------------------------------------------------------------------------
__global__ __launch_bounds__(256) void refine_q_kernel(
    const float* __restrict__ X, const float* __restrict__ Wq,
    const float* __restrict__ bq, const int* __restrict__ cnt,
    const int* __restrict__ wl, double* __restrict__ Q64)
{
    const int n = min(min(*cnt, WL_CAP), REF_SLOTS);
    const int slot0 = blockIdx.y * QT;
    if (slot0 >= n) return;
    const int ep0 = blockIdx.x * 64;
    const int t = threadIdx.x;

    __shared__ int rows[QT];
    __shared__ float As[32][QT + 4];   // [k][slot-row]
    __shared__ float Bs[32][68];       // [k][e'-col]
    if (t < QT) rows[t] = wl[min(slot0 + t, n - 1)];  // clamp: duplicate work, always valid
    __syncthreads();

    const int r  = t >> 4;         // slot-row 0..15
    const int cg = (t & 15) * 4;   // e' col group

    double acc[4] = {0.0, 0.0, 0.0, 0.0};

    for (int k0 = 0; k0 < E; k0 += 32) {
        if (t < 128) {
            const int ar = t >> 3, kc = (t & 7) * 4;
            const float4 a4 = *(const float4*)&X[(size_t)rows[ar] * E + k0 + kc];
            As[kc + 0][ar] = a4.x; As[kc + 1][ar] = a4.y;
            As[kc + 2][ar] = a4.z; As[kc + 3][ar] = a4.w;
        }
        {
            const int br = t >> 2, kc = (t & 3) * 8;
            const float4 b0 = *(const float4*)&Wq[(size_t)(ep0 + br) * E + k0 + kc];
            const float4 b1 = *(const float4*)&Wq[(size_t)(ep0 + br) * E + k0 + kc + 4];
            Bs[kc + 0][br] = b0.x; Bs[kc + 1][br] = b0.y;
            Bs[kc + 2][br] = b0.z; Bs[kc + 3][br] = b0.w;
            Bs[kc + 4][br] = b1.x; Bs[kc + 5][br] = b1.y;
            Bs[kc + 6][br] = b1.z; Bs[kc + 7][br] = b1.w;
        }
        __syncthreads();
#pragma unroll
        for (int k = 0; k < 32; ++k) {
            const double a = (double)As[k][r];
#pragma unroll
            for (int j = 0; j < 4; ++j)
                acc[j] = fma(a, (double)Bs[k][cg + j], acc[j]);
        }
        __syncthreads();
    }
#pragma unroll
    for (int j = 0; j < 4; ++j)
        Q64[(size_t)(slot0 + r) * E + ep0 + cg + j] = acc[j] + (double)bq[ep0 + cg + j];
}

// ---------------------------------------------------------------------------
// Kernel 4b: refine partial dots — partial[slot,c,h] over e'-chunk c.
// ---------------------------------------------------------------------------
__global__ __launch_bounds__(256) void refine_partial_kernel(
    const double* __restrict__ Q64, const double* __restrict__ K64T,
    const int* __restrict__ cnt, const int* __restrict__ wl,
    double* __restrict__ partials)
{
    const int slot = blockIdx.y;
    const int n = min(min(*cnt, WL_CAP), REF_SLOTS);
    if (slot >= n) return;

    const int t  = threadIdx.x;
    const int c  = blockIdx.x;      // e'-chunk 0..7
    const int e0 = c * 512;

    __shared__ __align__(16) double Qs[512];
    if (t < 128) {
        const double2 q0 = *(const double2*)&Q64[(size_t)slot * E + e0 + t * 4];
        const double2 q1 = *(const double2*)&Q64[(size_t)slot * E + e0 + t * 4 + 2];
        Qs[t * 4 + 0] = q0.x; Qs[t * 4 + 1] = q0.y;
        Qs[t * 4 + 2] = q1.x; Qs[t * 4 + 3] = q1.y;
    }
    __syncthreads();

    double a0 = 0, a1 = 0, a2 = 0, a3 = 0;
    for (int e = 0; e < 512; e += 4) {
        const size_t base = (size_t)(e0 + e) * HH + t;
        a0 = fma(Qs[e + 0], K64T[base + 0 * HH], a0);
        a1 = fma(Qs[e + 1], K64T[base + 1 * HH], a1);
        a2 = fma(Qs[e + 2], K64T[base + 2 * HH], a2);
        a3 = fma(Qs[e + 3], K64T[base + 3 * HH], a3);
    }
    partials[((size_t)slot * 8 + c) * HH + t] = (a0 + a1) + (a2 + a3);
}

// ---------------------------------------------------------------------------
// Kernel 4c: combine chunk-partials, block argmax (first-max, tie -> lower
// hub position, matching np.argmax). bq already folded into Q64.
// ---------------------------------------------------------------------------
__global__ __launch_bounds__(256) void refine_reduce_kernel(
    const double* __restrict__ partials, const int* __restrict__ hub,
    const int* __restrict__ cnt, const int* __restrict__ wl,
    int* __restrict__ out)
{
    const int slot = blockIdx.x;
    const int n = min(min(*cnt, WL_CAP), REF_SLOTS);
    if (slot >= n) return;

    const int t = threadIdx.x;
    double v = 0.0;
#pragma unroll
    for (int c = 0; c < 8; ++c)
        v += partials[((size_t)slot * 8 + c) * HH + t];

    __shared__ double rv[256];
    __shared__ int    ri[256];
    rv[t] = v; ri[t] = t;
    __syncthreads();
    for (int s = 128; s; s >>= 1) {
        if (t < s) {
            const bool better = rv[t + s] > rv[t] ||
                                (rv[t + s] == rv[t] && ri[t + s] < ri[t]);
            if (better) { rv[t] = rv[t + s]; ri[t] = ri[t + s]; }
        }
        __syncthreads();
    }
    if (t == 0) out[wl[slot]] = hub[ri[0]];
}

// ---------------------------------------------------------------------------
// Kernel 5: hub nodes map to themselves (isin override). Must run LAST.
// ---------------------------------------------------------------------------
__global__ void hub_override_kernel(const int* __restrict__ hub,
                                    int* __restrict__ out)
{
    const int t = threadIdx.x;
    if (t < HH) { const int h = hub[t]; out[h] = h; }
}

extern "C" void kernel_launch(void* const* d_in, const int* in_sizes, int n_in,
                              void* d_out, int out_size, void* d_ws, size_t ws_size,
                              hipStream_t stream) {
    const float* X   = (const float*)d_in[0];   // [NN, E]
    const int*   hub = (const int*)  d_in[1];   // [HH]
    const float* Wq  = (const float*)d_in[2];   // [E, E]
    const float* bq  = (const float*)d_in[3];   // [E]
    const float* Wk  = (const float*)d_in[4];   // [E, E]
    const float* bk  = (const float*)d_in[5];   // [E]
    int* out = (int*)d_out;                     // [NN]

    // workspace base layout (~21.0 MB):
    //   K64  [HH][E] d  8 MB   (dead after cvec32 -> Q64 aliases it)
    //   K64T [E][HH] d  8 MB   (live through refine)
    //   Sh,Sl [HH][E] bf16 2+2 MB (dead after scores -> refine partials alias)
    //   c32, cnt, wl            ~9 KB
    // k-split partials (KS x 8 MB) appended past BASE if ws_size allows.
    double*         K64  = (double*)d_ws;
    double*         K64T = K64 + (size_t)HH * E;
    unsigned short* Sh   = (unsigned short*)(K64T + (size_t)HH * E);
    unsigned short* Sl   = Sh + (size_t)HH * E;
    float*          c32  = (float*)(Sl + (size_t)HH * E);
    int*            cnt  = (int*)(c32 + HH);
    int*            wl   = cnt + 1;                 // [WL_CAP]
    double*         Q64  = K64;                     // [REF_SLOTS][E]    8 MB alias
    double*         rpart = (double*)Sh;            // [REF_SLOTS][8][HH] 4 MB alias

    const size_t BASE = 21000192;                   // 256-aligned, > fixed layout end
    const size_t slab = (size_t)HH * E * sizeof(double);   // 8 MB per k-slice
    int ks = 1;
    if      (ws_size >= BASE + 8 * slab) ks = 8;
    else if (ws_size >= BASE + 4 * slab) ks = 4;
    else if (ws_size >= BASE + 2 * slab) ks = 2;
    double* kpart = (double*)((char*)d_ws + BASE);

    init_kernel<<<dim3(1), 64, 0, stream>>>(cnt);
    if (ks > 1) {
        k_proj_part_kernel<<<dim3(E / 64, HH / 64, ks), 256, 0, stream>>>(
            X, hub, Wk, E / ks, kpart);
        k_reduce_kernel<<<dim3(E / 64, HH / 64), 256, 0, stream>>>(
            kpart, bk, ks, K64, K64T);
    } else {
        k_proj64_kernel<<<dim3(E / 64, HH / 64), 256, 0, stream>>>(
            X, hub, Wk, bk, K64, K64T);
    }
    s_proj_mfma_kernel<<<dim3(E / 64, HH / 64), 256, 0, stream>>>(K64, Wq, Sh, Sl);
    cvec32_kernel<<<dim3(HH), 256, 0, stream>>>(bq, K64, c32);
    scores_mfma_kernel<<<dim3(NN / 64), 512, 0, stream>>>(X, Sh, Sl, c32, hub, out, cnt, wl);
    refine_q_kernel<<<dim3(E / 64, REF_SLOTS / QT), 256, 0, stream>>>(X, Wq, bq, cnt, wl, Q64);
    refine_partial_kernel<<<dim3(8, REF_SLOTS), 256, 0, stream>>>(Q64, K64T, cnt, wl, rpart);
    refine_reduce_kernel<<<dim3(REF_SLOTS), 256, 0, stream>>>(rpart, hub, cnt, wl, out);
    hub_override_kernel<<<dim3(1), 256, 0, stream>>>(hub, out);
}